// Round 10
// baseline (15169.623 us; speedup 1.0000x reference)
//
#include <hip/hip_runtime.h>
#include <math.h>

// Problem constants
constexpr int T  = 512;
constexpr int B  = 64;
constexpr int I  = 1024;   // layer input width (layer1 input = 2*H = 1024)
constexpr int H  = 512;
constexpr int M  = T * B;

// Scan decomposition: group = R batch rows, split over SJ WGs (C cols each)
constexpr int R  = 4;
constexpr int SJ = 8;
constexpr int C  = 64;     // H / SJ
constexpr int NG = 16;     // groups per scan launch (one direction): B/R
constexpr int SPIN_MAX = 4096;  // ~1.7ms worst-case wait; expected ~10 polls

// ---------------------------------------------------------------------------
// xproj GEMM for ONE cell: P[row,h] = sum_i X[row,i]*nin[row&63,i]*Wih[h,i] + bih[h]
// grid = (M/128, H/128), 256 threads, 8x8 register blocking.
// ---------------------------------------------------------------------------
#define BM 128
#define BN 128
#define BK 32
#define LDP 132

__global__ __launch_bounds__(256) void gemm_xproj(
    const float* __restrict__ X,     // (M, I)
    const float* __restrict__ nin,   // (B, I)   cell-offset
    const float* __restrict__ wih,   // (H, I)   cell-offset
    const float* __restrict__ bih,   // (H)      cell-offset
    float* __restrict__ P)           // (M, H)
{
    const int bm = blockIdx.x;
    const int bn = blockIdx.y;

    __shared__ float As[BK][LDP];
    __shared__ float Bs[BK][LDP];

    const int tid = threadIdx.x;
    const int tx = tid % 16;
    const int ty = tid / 16;

    float acc[8][8];
#pragma unroll
    for (int i = 0; i < 8; ++i)
#pragma unroll
        for (int j = 0; j < 8; ++j) acc[i][j] = 0.f;

    const int kq    = (tid % 8) * 4;
    const int rbase = tid / 8;

    for (int k0 = 0; k0 < I; k0 += BK) {
#pragma unroll
        for (int p = 0; p < 4; ++p) {
            const int row_l = p * 32 + rbase;
            const int grow  = bm * BM + row_l;
            float4 a  = *(const float4*)&X[(size_t)grow * I + k0 + kq];
            float4 nn = *(const float4*)&nin[(size_t)(grow & (B - 1)) * I + k0 + kq];
            a.x *= nn.x; a.y *= nn.y; a.z *= nn.z; a.w *= nn.w;
            As[kq + 0][row_l] = a.x;
            As[kq + 1][row_l] = a.y;
            As[kq + 2][row_l] = a.z;
            As[kq + 3][row_l] = a.w;
        }
#pragma unroll
        for (int p = 0; p < 4; ++p) {
            const int hrow = p * 32 + rbase;
            float4 w = *(const float4*)&wih[(size_t)(bn * BN + hrow) * I + k0 + kq];
            Bs[kq + 0][hrow] = w.x;
            Bs[kq + 1][hrow] = w.y;
            Bs[kq + 2][hrow] = w.z;
            Bs[kq + 3][hrow] = w.w;
        }
        __syncthreads();

#pragma unroll
        for (int k = 0; k < BK; ++k) {
            float a[8], b[8];
            *(float4*)&a[0] = *(const float4*)&As[k][ty * 8];
            *(float4*)&a[4] = *(const float4*)&As[k][ty * 8 + 4];
            *(float4*)&b[0] = *(const float4*)&Bs[k][tx * 8];
            *(float4*)&b[4] = *(const float4*)&Bs[k][tx * 8 + 4];
#pragma unroll
            for (int i = 0; i < 8; ++i)
#pragma unroll
                for (int j = 0; j < 8; ++j)
                    acc[i][j] = fmaf(a[i], b[j], acc[i][j]);
        }
        __syncthreads();
    }

    const int grow0 = bm * BM + ty * 8;
    const int gcol0 = bn * BN + tx * 8;
    float bb[8];
#pragma unroll
    for (int j = 0; j < 8; ++j) bb[j] = bih[gcol0 + j];
#pragma unroll
    for (int i = 0; i < 8; ++i) {
        float4 o0, o1;
        o0.x = acc[i][0] + bb[0]; o0.y = acc[i][1] + bb[1];
        o0.z = acc[i][2] + bb[2]; o0.w = acc[i][3] + bb[3];
        o1.x = acc[i][4] + bb[4]; o1.y = acc[i][5] + bb[5];
        o1.z = acc[i][6] + bb[6]; o1.w = acc[i][7] + bb[7];
        *(float4*)&P[(size_t)(grow0 + i) * H + gcol0]     = o0;
        *(float4*)&P[(size_t)(grow0 + i) * H + gcol0 + 4] = o1;
    }
}

// ---------------------------------------------------------------------------
__global__ void zero_cnt(int* __restrict__ cnt) {
    cnt[blockIdx.x * 256 + threadIdx.x] = 0;   // grid 32 x 256 = 8192 = NG*T
}

// Scatter Ytmp (M,H) into Y.left (M,2H): dst[row*1024 + c] = src[row*512 + c]
__global__ void copy_left(const float* __restrict__ src, float* __restrict__ dst) {
    const size_t k = (size_t)blockIdx.x * 256 + threadIdx.x;  // float4 index
    const size_t row = k >> 7;           // k / 128
    const int    c4  = (int)(k & 127);
    *(float4*)&dst[row * 1024 + (size_t)c4 * 4] =
        *(const float4*)&src[row * 512 + (size_t)c4 * 4];
}

// ---------------------------------------------------------------------------
// One-direction j-split scan with register-resident weights.
// grid = 128 WGs x 256 threads. WG w: group g = w&15 (batch rows g*4..g*4+3),
// member mbr = w>>4 -> j-slice [mbr*64, mbr*64+64). W[jslice,:] lives in 128
// VGPRs/thread for the whole loop. Publish/peer-read buffer Yp is
// parameterized (row stride ldy): Y-half (ldy=1024) or Ytmp (ldy=512), so
// layer-1 dir-0 can publish without clobbering layer-0's output that
// layer-1 dir-1's GEMM still needs.
// ---------------------------------------------------------------------------
__global__ __launch_bounds__(256, 2) void rnn_scan_sync(
    const float* __restrict__ P,     // (M, H) this cell's xproj
    const float* __restrict__ mask,  // (T, B)
    const float* __restrict__ whh,   // (H, H) cell-offset
    const float* __restrict__ bhh,   // (H)    cell-offset
    const float* __restrict__ nh,    // (B, H) cell-offset
    float* __restrict__ Yp,          // publish base (col offset pre-folded)
    const int ldy,                   // row stride of Yp in floats
    float* __restrict__ hn,          // (B, H) cell-offset
    int* __restrict__ cnt,           // (NG, T)
    const int dir)
{
    const int w   = blockIdx.x;
    const int g   = w & 15;          // group = row-group
    const int mbr = w >> 4;          // 0..7
    const int jbase = mbr * C;
    const int tid = threadIdx.x;

    const int q   = tid >> 5;        // 0..7  (i-slice)
    const int jc2 = tid & 31;        // 0..31
    const int ur  = tid >> 6;        // 0..3  (update row)
    const int uj  = tid & 63;        // 0..63 (update col)

    __shared__ float u_lds[R][H];       // 8 KB
    __shared__ float nh_lds[R][H];      // 8 KB
    __shared__ float part[4][R][C];     // 4 KB
    __shared__ int   wg_dead;

    if (tid == 0) wg_dead = 0;
    for (int k = tid; k < R * H; k += 256) {
        const int r = k >> 9, i = k & 511;
        nh_lds[r][i] = nh[(size_t)(g * R + r) * H + i];
    }

    // resident weights: thread (q, jc2) holds W[{jbase+jc2, jbase+jc2+32}, q*64 .. q*64+63]
    float4 wreg[2][16];
#pragma unroll
    for (int jh = 0; jh < 2; ++jh) {
        const int j = jbase + jc2 + jh * 32;
#pragma unroll
        for (int c = 0; c < 16; ++c)
            wreg[jh][c] = *(const float4*)&whh[(size_t)j * H + q * 64 + c * 4];
    }

    float hreg = 0.f;
    const int   row  = g * R + ur;
    const float bias = bhh[jbase + uj];

    __syncthreads();   // nh_lds ready

    const int t0 = (dir == 0) ? 0 : T - 1;
    const int dt = (dir == 0) ? 1 : -1;

    for (int s = 0; s < T; ++s) {
        const int t = t0 + dt * s;

        const float pval = P[((size_t)t * B + row) * H + jbase + uj];
        const float mval = mask[(size_t)t * B + row];

        // ---- acquire peer h of step s-1, stage u = h * nh ----
        if (s == 0) {
            for (int k = tid; k < R * H; k += 256) ((float*)u_lds)[k] = 0.f;
        } else {
            if (tid == 0 && wg_dead == 0) {
                int spins = 0;
                while (__hip_atomic_load(&cnt[g * T + (s - 1)], __ATOMIC_ACQUIRE,
                                         __HIP_MEMORY_SCOPE_AGENT) < SJ) {
                    if (++spins >= SPIN_MAX) { wg_dead = 1; break; }
                    __builtin_amdgcn_s_sleep(8);
                }
            }
            __syncthreads();
            const int tprev = t - dt;
#pragma unroll
            for (int k = 0; k < 8; ++k) {
                const int idx = tid + k * 256;           // 0..2047
                const int r = idx >> 9, i = idx & 511;
                const float h = __hip_atomic_load(
                    &Yp[((size_t)tprev * B + g * R + r) * (size_t)ldy + i],
                    __ATOMIC_RELAXED, __HIP_MEMORY_SCOPE_AGENT);
                u_lds[r][i] = h * nh_lds[r][i];
            }
        }
        __syncthreads();   // u_lds ready

        // ---- matvec from register-resident weights ----
        float acc[R][2];
#pragma unroll
        for (int r = 0; r < R; ++r) { acc[r][0] = 0.f; acc[r][1] = 0.f; }
#pragma unroll
        for (int c = 0; c < 16; ++c) {
            float4 uv[R];
#pragma unroll
            for (int r = 0; r < R; ++r)
                uv[r] = *(const float4*)&u_lds[r][q * 64 + c * 4];
#pragma unroll
            for (int jh = 0; jh < 2; ++jh) {
                const float4 wv = wreg[jh][c];
#pragma unroll
                for (int r = 0; r < R; ++r)
                    acc[r][jh] += wv.x * uv[r].x + wv.y * uv[r].y +
                                  wv.z * uv[r].z + wv.w * uv[r].w;
            }
        }
#pragma unroll
        for (int r = 0; r < R; ++r) {
#pragma unroll
            for (int jh = 0; jh < 2; ++jh)
                acc[r][jh] += __shfl_xor(acc[r][jh], 32);
        }
        const int wv_id = tid >> 6;
#pragma unroll
        for (int r = 0; r < R; ++r) {
            part[wv_id][r][jc2]      = acc[r][0];
            part[wv_id][r][jc2 + 32] = acc[r][1];
        }
        __syncthreads();

        // ---- h update ----
        const float pre = part[0][ur][uj] + part[1][ur][uj] +
                          part[2][ur][uj] + part[3][ur][uj];
        const float th   = tanhf(pre + pval + bias);
        const float hnew = th * mval + hreg * (1.f - mval);
        hreg = hnew;
        __hip_atomic_store(
            &Yp[((size_t)t * B + row) * (size_t)ldy + jbase + uj],
            hnew, __ATOMIC_RELAXED, __HIP_MEMORY_SCOPE_AGENT);
        __syncthreads();   // drains all threads' Y stores before the arrival

        if (tid == 0)
            __hip_atomic_fetch_add(&cnt[g * T + s], 1, __ATOMIC_RELEASE,
                                   __HIP_MEMORY_SCOPE_AGENT);
    }

    hn[(size_t)row * H + jbase + uj] = hreg;
}

// ---------------------------------------------------------------------------
// Launch choreography (buffer lifetimes; ws = P(64MiB) + Ytmp(64MiB) = 128MiB):
//  1. gemm c0 (input -> P);  scan c0 -> Y.left   (cnt @ Ytmp: dead region)
//  2. gemm c1 (input -> P);  scan c1 -> Y.right  (cnt @ Ytmp)
//  3. gemm c2 (Y -> P);      scan c2 -> Ytmp     (cnt @ hn[3] region of d_out,
//                                                 overwritten later by real hn)
//  4. gemm c3 (old Y -> P);  copy Ytmp -> Y.left; scan c3 -> Y.right
//                                                 (cnt @ Ytmp: dead after copy)
// ---------------------------------------------------------------------------
extern "C" void kernel_launch(void* const* d_in, const int* in_sizes, int n_in,
                              void* d_out, int out_size, void* d_ws, size_t ws_size,
                              hipStream_t stream) {
    const float* input = (const float*)d_in[0];
    const float* mask  = (const float*)d_in[1];
    const float* w_ih  = (const float*)d_in[2];
    const float* w_hh  = (const float*)d_in[3];
    const float* b_ih  = (const float*)d_in[4];
    const float* b_hh  = (const float*)d_in[5];
    const float* p_nin = (const float*)d_in[6];
    const float* p_nh  = (const float*)d_in[7];

    float* out_x  = (float*)d_out;                    // (T,B,2H) = (M,1024)
    float* out_hn = out_x + (size_t)M * (2 * H);      // (4,B,H)
    float* P      = (float*)d_ws;                     // (M,H) = 64 MiB
    float* Ytmp   = P + (size_t)M * H;                // (M,H) = 64 MiB
    int*   cntA   = (int*)Ytmp;                       // cnt in dead Ytmp region
    int*   cntB   = (int*)(out_hn + (size_t)3 * B * H); // cnt in hn[3] region

    const dim3 ggrid(M / BM, H / BN);

    for (int layer = 0; layer < 2; ++layer) {
        const float* X = (layer == 0) ? input : out_x;
        for (int dir = 0; dir < 2; ++dir) {
            const int cell = layer * 2 + dir;
            const bool detour = (layer == 1 && dir == 0);  // publish via Ytmp
            float* Yp  = detour ? Ytmp : (out_x + (size_t)dir * H);
            int    ldy = detour ? H : 2 * H;
            int*   cnt = detour ? cntB : cntA;

            gemm_xproj<<<ggrid, 256, 0, stream>>>(
                X,
                p_nin + (size_t)cell * B * I,
                w_ih + (size_t)cell * H * I,
                b_ih + (size_t)cell * H,
                P);
            if (layer == 1 && dir == 1) {
                // gemm c3 has read old Y.left; now land layer1-dir0 output
                copy_left<<<M * H / 4 / 256, 256, 0, stream>>>(Ytmp, out_x);
            }
            zero_cnt<<<32, 256, 0, stream>>>(cnt);
            rnn_scan_sync<<<128, 256, 0, stream>>>(
                P, mask,
                w_hh + (size_t)cell * H * H,
                b_hh + (size_t)cell * H,
                p_nh + (size_t)cell * B * H,
                Yp, ldy,
                out_hn + (size_t)cell * B * H,
                cnt, dir);
        }
    }
}